// Round 15
// baseline (87.546 us; speedup 1.0000x reference)
//
#include <hip/hip_runtime.h>
#include <hip/hip_fp16.h>
#include <cstdint>

#define VOCAB 50000
#define EMB   300
#define SEQ   80
#define HID   128
#define BATCH 4096

typedef __attribute__((ext_vector_type(8))) _Float16 f16x8;
typedef __attribute__((ext_vector_type(4))) float    f32x4;

static __device__ __forceinline__ float fast_tanh(float xv) {
    const float e = __expf(2.f * xv);
    float r;
    asm("v_rcp_f32 %0, %1" : "=v"(r) : "v"(e + 1.f));
    return fmaf(-2.f, r, 1.f);
}
static __device__ __forceinline__ float f16b2f(unsigned short u) {
    _Float16 h; __builtin_memcpy(&h, &u, 2); return (float)h;
}
static __device__ __forceinline__ unsigned pack2h(float a, float b) {
    _Float16 ha = (_Float16)a, hb = (_Float16)b;
    unsigned short ua, ub;
    __builtin_memcpy(&ua, &ha, 2); __builtin_memcpy(&ub, &hb, 2);
    return (unsigned)ua | ((unsigned)ub << 16);
}

// ---------------------------------------------------------------------------
// k_wprep: fragment-ordered fp16 Wxh table (for k_ptab).
//  c=(ks,col,g): W2[c][j] = Wxh[32ks+8g+j][col], zero-padded past K=300.
// ---------------------------------------------------------------------------
__global__ __launch_bounds__(256) void k_wprep(const float* __restrict__ Wxh,
                                               _Float16* __restrict__ W2) {
    const int c = blockIdx.x * 256 + threadIdx.x;
    if (c >= 5120) return;
    const int ks = c >> 9, rem = c & 511, col = rem >> 2, g = rem & 3;
    f16x8 f;
    #pragma unroll
    for (int j = 0; j < 8; ++j) {
        const int k = 32 * ks + 8 * g + j;
        f[j] = (_Float16)(k < EMB ? Wxh[k * HID + col] : 0.f);
    }
    *reinterpret_cast<f16x8*>(W2 + (size_t)c * 8) = f;
}

// ---------------------------------------------------------------------------
// k_ptab: P[v][c] = fp16( emb[v] @ Wxh + bh ), bh folded. BARRIER-FREE
// register-direct structure (R9/R14-verified). launch_bounds(256,3):
// 12 waves/CU for more streaming TLP (VGPR cap 170 > ~140 used).
// ---------------------------------------------------------------------------
__global__ __launch_bounds__(256, 3) void k_ptab(
    const float*    __restrict__ emb,  // [VOCAB][300]
    const _Float16* __restrict__ W2,   // Wxh frag table
    const float*    __restrict__ bh,   // [128]
    _Float16*       __restrict__ P)    // [VOCAB][128] fp16
{
    const int tid = threadIdx.x, lane = tid & 63;
    const int wv = tid >> 6, r16 = lane & 15, g = lane >> 4;
    const int row = blockIdx.x * 64 + wv * 16 + r16;
    const float* rp = emb + (size_t)(row < VOCAB ? row : VOCAB - 1) * EMB;
    const bool wr = (row < VOCAB);

    f16x8 ef[10];
    #pragma unroll
    for (int ks = 0; ks < 9; ++ks) {
        const float4 u0 = *reinterpret_cast<const float4*>(rp + 32 * ks + 8 * g);
        const float4 u1 = *reinterpret_cast<const float4*>(rp + 32 * ks + 8 * g + 4);
        f16x8 f;
        f[0] = (_Float16)u0.x; f[1] = (_Float16)u0.y;
        f[2] = (_Float16)u0.z; f[3] = (_Float16)u0.w;
        f[4] = (_Float16)u1.x; f[5] = (_Float16)u1.y;
        f[6] = (_Float16)u1.z; f[7] = (_Float16)u1.w;
        ef[ks] = f;
    }
    {
        f16x8 f;
        #pragma unroll
        for (int j = 0; j < 8; ++j) f[j] = (_Float16)0.f;
        if (g == 0) {
            const float4 u0 = *reinterpret_cast<const float4*>(rp + 288);
            const float4 u1 = *reinterpret_cast<const float4*>(rp + 292);
            f[0] = (_Float16)u0.x; f[1] = (_Float16)u0.y;
            f[2] = (_Float16)u0.z; f[3] = (_Float16)u0.w;
            f[4] = (_Float16)u1.x; f[5] = (_Float16)u1.y;
            f[6] = (_Float16)u1.z; f[7] = (_Float16)u1.w;
        } else if (g == 1) {
            const float4 u0 = *reinterpret_cast<const float4*>(rp + 296);
            f[0] = (_Float16)u0.x; f[1] = (_Float16)u0.y;
            f[2] = (_Float16)u0.z; f[3] = (_Float16)u0.w;
        }
        ef[9] = f;
    }

    float4 bhf[8];
    #pragma unroll
    for (int ct = 0; ct < 8; ++ct)
        bhf[ct] = *reinterpret_cast<const float4*>(bh + 16 * ct + 4 * g);

    f16x8 wA[10], wB[10];
    #pragma unroll
    for (int ks = 0; ks < 10; ++ks)
        wA[ks] = *reinterpret_cast<const f16x8*>(
            W2 + ((size_t)ks * 512 + (size_t)r16 * 4 + g) * 8);

    unsigned short* const po = (unsigned short*)P + (size_t)(wr ? row : 0) * HID;

    #pragma unroll
    for (int ct = 0; ct < 8; ++ct) {
        if (ct < 7) {
            const int coln = 16 * (ct + 1) + r16;
            #pragma unroll
            for (int ks = 0; ks < 10; ++ks)
                ((ct & 1) ? wA : wB)[ks] = *reinterpret_cast<const f16x8*>(
                    W2 + ((size_t)ks * 512 + (size_t)coln * 4 + g) * 8);
        }
        const f16x8* wc = (ct & 1) ? wB : wA;
        f32x4 a0 = {0.f, 0.f, 0.f, 0.f}, a1 = {0.f, 0.f, 0.f, 0.f};
        #pragma unroll
        for (int ks = 0; ks < 10; ks += 2) {
            a0 = __builtin_amdgcn_mfma_f32_16x16x32_f16(wc[ks],     ef[ks],     a0, 0, 0, 0);
            a1 = __builtin_amdgcn_mfma_f32_16x16x32_f16(wc[ks + 1], ef[ks + 1], a1, 0, 0, 0);
        }
        uint2 o;
        o.x = pack2h(a0[0] + a1[0] + bhf[ct].x, a0[1] + a1[1] + bhf[ct].y);
        o.y = pack2h(a0[2] + a1[2] + bhf[ct].z, a0[3] + a1[3] + bhf[ct].w);
        if (wr) *reinterpret_cast<uint2*>(po + ct * 16 + g * 4) = o;
    }
}

// ---------------------------------------------------------------------------
// k_rnn: R7 step VERBATIM, but 1024-thr blocks hold TWO independent 16-row
// groups (waves 0-7 = group A, 8-15 = group B; own Xb/Hb each). Grid 128
// -> 16 waves/CU = 4 waves/SIMD: while one group's waves sit in their
// serial ds_read->MFMA->tanh chain, the other group's issue. The single
// s_barrier over-syncs both groups (correctness unaffected).
// Swapped-operand MFMA: mfma(wh[ks], h_frag[ks], acc) -> D lane (g,r16)
// reg r = h_new[row r16][col 16wv+4g+r]; XOR-16B swizzle throughout.
// ---------------------------------------------------------------------------
__global__ __launch_bounds__(1024, 1) void k_rnn(
    const int*      __restrict__ x,    // [BATCH][SEQ]
    const _Float16* __restrict__ P,    // [VOCAB][128] fp16 (bh folded)
    const float*    __restrict__ Whh,  // [128][128]
    const float*    __restrict__ Wd,   // [128]
    const float*    __restrict__ bd,   // [1]
    float*          __restrict__ out)  // [BATCH]
{
    __shared__ __align__(16) unsigned char Xb[2][2][4096];  // [grp][parity]
    __shared__ __align__(16) unsigned char Hb[2][2][4096];  // [grp][parity]
    __shared__ int xidx[32 * SEQ];

    const int tid = threadIdx.x;
    const int grp = tid >> 9;           // 0 or 1
    const int t9  = tid & 511;          // R7-equivalent tid within group
    const int lane = tid & 63;
    const int wv = t9 >> 6;             // 0..7 within group
    const int r16 = lane & 15, g = lane >> 4;
    const int rb = blockIdx.x * 32 + grp * 16;

    for (int q = tid; q < 32 * SEQ; q += 1024)
        xidx[q] = x[blockIdx.x * 32 * SEQ + q];
    if (t9 < 256) { uint4 z = {}; *reinterpret_cast<uint4*>(&Hb[grp][0][t9 * 16]) = z; }

    const int* const xg = xidx + grp * 16 * SEQ;
    const int col = 16 * wv + r16;

    int h_rd[4];
    #pragma unroll
    for (int ks = 0; ks < 4; ++ks)
        h_rd[ks] = r16 * 256 + (((4 * ks + g) ^ r16) & 15) * 16;
    const int hw = r16 * 256 + (((2 * wv + (g >> 1)) ^ r16) & 15) * 16 + (g & 1) * 8;

    // Whh fragments (one-time strided loads; same for both groups)
    f16x8 wh[4];
    #pragma unroll
    for (int ks = 0; ks < 4; ++ks) {
        f16x8 f;
        #pragma unroll
        for (int j = 0; j < 8; ++j)
            f[j] = (_Float16)Whh[(32 * ks + 8 * g + j) * HID + col];
        wh[ks] = f;
    }

    const bool gon  = (t9 < 256);
    const int  grow = (t9 >> 4) & 15, gk = t9 & 15;
    const int  gdst = grow * 256 + ((gk ^ grow) & 15) * 16;

    __syncthreads();  // xidx + h0 ready

    if (gon)
        *reinterpret_cast<uint4*>(&Xb[grp][0][gdst]) = *reinterpret_cast<const uint4*>(
            P + (size_t)xg[grow * SEQ] * HID + 8 * gk);
    uint4 cur = {}, nxt = {};
    if (gon) cur = *reinterpret_cast<const uint4*>(
        P + (size_t)xg[grow * SEQ + 1] * HID + 8 * gk);

    asm volatile("s_waitcnt lgkmcnt(0)" ::: "memory");
    __builtin_amdgcn_s_barrier();
    __builtin_amdgcn_sched_barrier(0);

#define STEP(T, PB, CUR, NXT)                                                      \
    {                                                                              \
        if ((T) + 1 < SEQ && gon)                                                  \
            *reinterpret_cast<uint4*>(&Xb[grp][(PB) ^ 1][gdst]) = CUR;             \
        if ((T) + 2 < SEQ && gon)                                                  \
            NXT = *reinterpret_cast<const uint4*>(                                 \
                P + (size_t)xg[grow * SEQ + (T) + 2] * HID + 8 * gk);              \
        const uint2 xv = *reinterpret_cast<const uint2*>(&Xb[grp][PB][hw]);        \
        f32x4 accA, accB = {0.f, 0.f, 0.f, 0.f};                                   \
        accA[0] = f16b2f((unsigned short)(xv.x & 0xffff));                         \
        accA[1] = f16b2f((unsigned short)(xv.x >> 16));                            \
        accA[2] = f16b2f((unsigned short)(xv.y & 0xffff));                         \
        accA[3] = f16b2f((unsigned short)(xv.y >> 16));                            \
        const f16x8 h0 = *reinterpret_cast<const f16x8*>(&Hb[grp][PB][h_rd[0]]);   \
        const f16x8 h1 = *reinterpret_cast<const f16x8*>(&Hb[grp][PB][h_rd[1]]);   \
        const f16x8 h2 = *reinterpret_cast<const f16x8*>(&Hb[grp][PB][h_rd[2]]);   \
        const f16x8 h3 = *reinterpret_cast<const f16x8*>(&Hb[grp][PB][h_rd[3]]);   \
        accA = __builtin_amdgcn_mfma_f32_16x16x32_f16(wh[0], h0, accA, 0, 0, 0);   \
        accB = __builtin_amdgcn_mfma_f32_16x16x32_f16(wh[1], h1, accB, 0, 0, 0);   \
        accA = __builtin_amdgcn_mfma_f32_16x16x32_f16(wh[2], h2, accA, 0, 0, 0);   \
        accB = __builtin_amdgcn_mfma_f32_16x16x32_f16(wh[3], h3, accB, 0, 0, 0);   \
        uint2 hv;                                                                  \
        hv.x = pack2h(fast_tanh(accA[0] + accB[0]), fast_tanh(accA[1] + accB[1])); \
        hv.y = pack2h(fast_tanh(accA[2] + accB[2]), fast_tanh(accA[3] + accB[3])); \
        *reinterpret_cast<uint2*>(&Hb[grp][(PB) ^ 1][hw]) = hv;                    \
        asm volatile("s_waitcnt lgkmcnt(0)" ::: "memory");                         \
        __builtin_amdgcn_s_barrier();                                              \
        __builtin_amdgcn_sched_barrier(0);                                         \
    }

    for (int t = 0; t < SEQ; t += 2) {
        STEP(t,     0, cur, nxt);
        STEP(t + 1, 1, nxt, cur);
    }
#undef STEP

    // ---- final dense + sigmoid: h(79) in Hb[grp][0]; 32 thr per batch row --
    const char* hb0 = (const char*)&Hb[grp][0][0];
    const int r = t9 >> 5, m = t9 & 31;   // r 0..15, cols 4m..4m+3
    const int fb = r * 256 + (((m >> 1) ^ r) & 15) * 16 + (m & 1) * 8;
    const uint2 hv = *reinterpret_cast<const uint2*>(hb0 + fb);
    const float4 wd = *reinterpret_cast<const float4*>(&Wd[4 * m]);
    float part = f16b2f((unsigned short)(hv.x & 0xffff)) * wd.x
               + f16b2f((unsigned short)(hv.x >> 16))    * wd.y
               + f16b2f((unsigned short)(hv.y & 0xffff)) * wd.z
               + f16b2f((unsigned short)(hv.y >> 16))    * wd.w;
    part += __shfl_down(part, 16, 32);
    part += __shfl_down(part, 8, 32);
    part += __shfl_down(part, 4, 32);
    part += __shfl_down(part, 2, 32);
    part += __shfl_down(part, 1, 32);
    if (m == 0) out[rb + r] = 1.f / (1.f + expf(-(part + bd[0])));
}

// ---------------------------------------------------------------------------
extern "C" void kernel_launch(void* const* d_in, const int* in_sizes, int n_in,
                              void* d_out, int out_size, void* d_ws, size_t ws_size,
                              hipStream_t stream)
{
    (void)in_sizes; (void)n_in; (void)out_size; (void)ws_size;
    const int*   x   = (const int*)  d_in[0];
    const float* emb = (const float*)d_in[1];
    const float* Wxh = (const float*)d_in[2];
    const float* Whh = (const float*)d_in[3];
    const float* bh  = (const float*)d_in[4];
    const float* Wd  = (const float*)d_in[5];
    const float* bd  = (const float*)d_in[6];
    float* out = (float*)d_out;

    _Float16* P  = (_Float16*)d_ws;                          // 12.8 MB fp16
    _Float16* W2 = (_Float16*)((char*)d_ws + 12800000);      // 80 KB

    k_wprep<<<20, 256, 0, stream>>>(Wxh, W2);
    k_ptab<<<(VOCAB + 63) / 64, 256, 0, stream>>>(emb, W2, bh, P);
    k_rnn<<<BATCH / 32, 1024, 0, stream>>>(x, P, Whh, Wd, bd, out);
}